// Round 2
// baseline (785.006 us; speedup 1.0000x reference)
//
#include <hip/hip_runtime.h>
#include <math.h>

#define BB 2
#define LL 1024
#define CCH 512
#define HH 8
#define DD 64
#define LN_EPSF 1e-5f

__device__ __forceinline__ float wave_max(float v) {
#pragma unroll
  for (int off = 32; off > 0; off >>= 1) v = fmaxf(v, __shfl_xor(v, off));
  return v;
}
__device__ __forceinline__ float wave_sum(float v) {
#pragma unroll
  for (int off = 32; off > 0; off >>= 1) v += __shfl_xor(v, off);
  return v;
}
// broadcast lane `l` of v to all lanes via v_readlane (VALU pipe, not LDS)
__device__ __forceinline__ float bcast(float v, int l) {
  return __int_as_float(__builtin_amdgcn_readlane(__float_as_int(v), l));
}

// ---------------- LayerNorm: one block per row of 512 ----------------
__global__ __launch_bounds__(256) void ln_kernel(const float* __restrict__ f,
                                                 const float* __restrict__ g,
                                                 const float* __restrict__ bta,
                                                 float* __restrict__ x) {
  const int row = blockIdx.x;
  const int tid = threadIdx.x;
  const int wave = tid >> 6, lane = tid & 63;
  __shared__ float red[8];
  const float* fr = f + (size_t)row * CCH;
  float2 v = *(const float2*)&fr[tid * 2];
  float s = wave_sum(v.x + v.y);
  if (lane == 0) red[wave] = s;
  __syncthreads();
  float mu = (red[0] + red[1] + red[2] + red[3]) * (1.0f / CCH);
  float dx = v.x - mu, dy = v.y - mu;
  float sq = wave_sum(dx * dx + dy * dy);
  if (lane == 0) red[4 + wave] = sq;
  __syncthreads();
  float var = (red[4] + red[5] + red[6] + red[7]) * (1.0f / CCH);
  float inv = 1.0f / sqrtf(var + LN_EPSF);
  float2 gg = *(const float2*)&g[tid * 2];
  float2 bb = *(const float2*)&bta[tid * 2];
  float2 o;
  o.x = dx * inv * gg.x + bb.x;
  o.y = dy * inv * gg.y + bb.y;
  *(float2*)&x[(size_t)row * CCH + tid * 2] = o;
}

// ---------------- Row-wave GEMM core ----------------
// Block = 256 threads = 4 waves. Wave w computes rows [m0+w*16, +16),
// lane = output column n0+lane (64 cols). A rows are read with wave-uniform
// addresses (-> scalar s_load path); B tile staged in LDS, read 1 b32/lane/k.
__device__ __forceinline__ void rowwave_gemm_core(
    const float* __restrict__ A,     // [M,512] row-major
    const float* __restrict__ W,     // [512, Nld]
    const float* __restrict__ bias,  // [Nld]
    float* __restrict__ out,         // [M, Nld]
    int m0, int n0, int Nld, float* Bs /* [64*64] */) {
  const int tid = threadIdx.x;
  const int wave = __builtin_amdgcn_readfirstlane(tid >> 6);
  const int lane = tid & 63;
  int valid = Nld - n0;
  if (valid > 64) valid = 64;

  float acc[16];
#pragma unroll
  for (int r = 0; r < 16; ++r) acc[r] = 0.f;

  for (int k0 = 0; k0 < 512; k0 += 64) {
    __syncthreads();  // previous tile's reads done
#pragma unroll
    for (int i = 0; i < 4; ++i) {
      int e = i * 256 + tid;
      int k = e >> 4, c4 = e & 15;
      float4 b4;
      if (c4 * 4 + 3 < valid) {
        b4 = *(const float4*)&W[(size_t)(k0 + k) * Nld + n0 + c4 * 4];
      } else {
        b4.x = b4.y = b4.z = b4.w = 0.f;  // masked at store; avoids OOB
      }
      *(float4*)&Bs[k * 64 + c4 * 4] = b4;
    }
    __syncthreads();
    const float* Aw = A + (size_t)(m0 + wave * 16) * 512 + k0;
#pragma unroll
    for (int k4 = 0; k4 < 16; ++k4) {
      float b0 = Bs[(k4 * 4 + 0) * 64 + lane];
      float b1 = Bs[(k4 * 4 + 1) * 64 + lane];
      float b2 = Bs[(k4 * 4 + 2) * 64 + lane];
      float b3 = Bs[(k4 * 4 + 3) * 64 + lane];
#pragma unroll
      for (int r = 0; r < 16; ++r) {
        float4 a = *(const float4*)(Aw + (size_t)r * 512 + k4 * 4);  // uniform -> s_load
        acc[r] = fmaf(a.x, b0, acc[r]);
        acc[r] = fmaf(a.y, b1, acc[r]);
        acc[r] = fmaf(a.z, b2, acc[r]);
        acc[r] = fmaf(a.w, b3, acc[r]);
      }
    }
  }
  if (lane < valid) {
    float bv = bias[n0 + lane];
#pragma unroll
    for (int r = 0; r < 16; ++r)
      out[(size_t)(m0 + wave * 16 + r) * Nld + n0 + lane] = acc[r] + bv;
  }
}

// Fused q/k/v/qp/kp projections. grid.x in [0,28): 8+8+8+2+2 column tiles.
__global__ __launch_bounds__(256) void proj_fused(
    const float* __restrict__ x, const float* __restrict__ wq,
    const float* __restrict__ bq, const float* __restrict__ wk,
    const float* __restrict__ bk, const float* __restrict__ wv,
    const float* __restrict__ bv, const float* __restrict__ wqp,
    const float* __restrict__ bqp, const float* __restrict__ wkp,
    const float* __restrict__ bkp, float* __restrict__ qsb,
    float* __restrict__ ksb, float* __restrict__ vsb,
    float* __restrict__ qpb, float* __restrict__ kpb) {
  __shared__ float Bs[64 * 64];
  const int bx = blockIdx.x;
  const int m0 = blockIdx.y * 64;
  const float *W, *bias;
  float* out;
  int Nld, n0;
  if (bx < 8) { W = wq; bias = bq; out = qsb; Nld = 512; n0 = bx * 64; }
  else if (bx < 16) { W = wk; bias = bk; out = ksb; Nld = 512; n0 = (bx - 8) * 64; }
  else if (bx < 24) { W = wv; bias = bv; out = vsb; Nld = 512; n0 = (bx - 16) * 64; }
  else if (bx < 26) { W = wqp; bias = bqp; out = qpb; Nld = 96; n0 = (bx - 24) * 64; }
  else { W = wkp; bias = bkp; out = kpb; Nld = 96; n0 = (bx - 26) * 64; }
  rowwave_gemm_core(x, W, bias, out, m0, n0, Nld, Bs);
}

// Output projection (same core). grid (8, 32).
__global__ __launch_bounds__(256) void out_proj(const float* __restrict__ A,
                                                const float* __restrict__ wo,
                                                const float* __restrict__ bo,
                                                float* __restrict__ out) {
  __shared__ float Bs[64 * 64];
  rowwave_gemm_core(A, wo, bo, out, blockIdx.y * 64, blockIdx.x * 64, 512, Bs);
}

// ---------------- Fused flash-style IPA attention, v2 ----------------
// grid: (32 Q-tiles of 32 rows, B*H). block 256 = 4 waves; wave w owns 8 rows.
// Scores: lane = key j; Q held in registers lane=d, broadcast via readlane.
// PV: lane = d; P broadcast via readlane (no LDS transpose). V from global.
__global__ __launch_bounds__(256) void ipa_attn2(
    const float* __restrict__ qsg, const float* __restrict__ ksg,
    const float* __restrict__ vsg, const float* __restrict__ qpg,
    const float* __restrict__ kpg, const float* __restrict__ pscale,
    float* __restrict__ outs) {
  const int qt = blockIdx.x;
  const int bh = blockIdx.y;
  const int b = bh >> 3, h = bh & 7;
  const int tid = threadIdx.x;
  const int wave = tid >> 6, lane = tid & 63;
  const float ps_h = pscale[h];

  __shared__ float ks[64 * 65];  // K^T [d][j], stride 65 (conflict-free both ways)
  __shared__ float kp[12 * 64];  // Kp [c][j]
  __shared__ float ksq[64];      // ps * |kp|^2 per key

  const int i0 = qt * 32 + wave * 8;  // this wave's first Q row

  float qreg[8], qpreg[8], qsqv[8];
#pragma unroll
  for (int r = 0; r < 8; ++r) {
    qreg[r] = qsg[((size_t)(b * LL + i0 + r)) * CCH + h * DD + lane] * 0.125f;
    float qp = (lane < 12) ? qpg[((size_t)(b * LL + i0 + r)) * 96 + h * 12 + lane] : 0.f;
    qsqv[r] = ps_h * wave_sum(qp * qp);
    qpreg[r] = qp * (2.f * ps_h);
  }

  float O[8], m[8], l[8];
#pragma unroll
  for (int r = 0; r < 8; ++r) { O[r] = 0.f; m[r] = -INFINITY; l[r] = 0.f; }

  for (int kt = 0; kt < 16; ++kt) {
    const int j0 = kt * 64;
    __syncthreads();  // previous tile's LDS reads done
#pragma unroll
    for (int i = 0; i < 4; ++i) {
      int e = i * 256 + tid;
      int j = e >> 4, d4 = e & 15;
      float4 k4 = *(const float4*)&ksg[((size_t)(b * LL + j0 + j)) * CCH + h * DD + d4 * 4];
      ks[(d4 * 4 + 0) * 65 + j] = k4.x;
      ks[(d4 * 4 + 1) * 65 + j] = k4.y;
      ks[(d4 * 4 + 2) * 65 + j] = k4.z;
      ks[(d4 * 4 + 3) * 65 + j] = k4.w;
    }
    if (tid < 64) {
      float a = 0.f;
      const float* kpr = &kpg[((size_t)(b * LL + j0 + tid)) * 96 + h * 12];
#pragma unroll
      for (int c = 0; c < 12; ++c) {
        float v = kpr[c];
        kp[c * 64 + tid] = v;
        a += v * v;
      }
      ksq[tid] = ps_h * a;
    }
    __syncthreads();

    float s[8];
#pragma unroll
    for (int r = 0; r < 8; ++r) s[r] = 0.f;
#pragma unroll 16
    for (int d = 0; d < 64; ++d) {
      float kd = ks[d * 65 + lane];
#pragma unroll
      for (int r = 0; r < 8; ++r) s[r] = fmaf(bcast(qreg[r], d), kd, s[r]);
    }
#pragma unroll
    for (int c = 0; c < 12; ++c) {
      float kpc = kp[c * 64 + lane];
#pragma unroll
      for (int r = 0; r < 8; ++r) s[r] = fmaf(bcast(qpreg[r], c), kpc, s[r]);
    }
    float ksqv = ksq[lane];
#pragma unroll
    for (int r = 0; r < 8; ++r) s[r] -= qsqv[r] + ksqv;

// online softmax; p stays in s[] (lane = j)
#pragma unroll
    for (int r = 0; r < 8; ++r) {
      float mt = wave_max(s[r]);
      float mnew = fmaxf(m[r], mt);
      float p = __expf(s[r] - mnew);
      float alpha = __expf(m[r] - mnew);
      l[r] = l[r] * alpha + wave_sum(p);
      O[r] *= alpha;
      m[r] = mnew;
      s[r] = p;
    }

// PV: lane = d; V straight from global (coalesced, L1/L2-hot)
#pragma unroll 16
    for (int j = 0; j < 64; ++j) {
      float vv = vsg[((size_t)(b * LL + j0 + j)) * CCH + h * DD + lane];
#pragma unroll
      for (int r = 0; r < 8; ++r) O[r] = fmaf(bcast(s[r], j), vv, O[r]);
    }
  }
#pragma unroll
  for (int r = 0; r < 8; ++r)
    outs[((size_t)(b * LL + i0 + r)) * CCH + h * DD + lane] = O[r] / l[r];
}

extern "C" void kernel_launch(void* const* d_in, const int* in_sizes, int n_in,
                              void* d_out, int out_size, void* d_ws, size_t ws_size,
                              hipStream_t stream) {
  (void)in_sizes; (void)n_in; (void)out_size; (void)ws_size;
  const float* features = (const float*)d_in[0];
  // d_in[1] = coords: unused by reference
  const float* ln_g = (const float*)d_in[2];
  const float* ln_b = (const float*)d_in[3];
  const float* wq = (const float*)d_in[4];
  const float* bq = (const float*)d_in[5];
  const float* wk = (const float*)d_in[6];
  const float* bk = (const float*)d_in[7];
  const float* wv = (const float*)d_in[8];
  const float* bv = (const float*)d_in[9];
  const float* wqp = (const float*)d_in[10];
  const float* bqp = (const float*)d_in[11];
  const float* wkp = (const float*)d_in[12];
  const float* bkp = (const float*)d_in[13];
  // d_in[14]/d_in[15] = wvp/bvp: unused by reference
  const float* wo = (const float*)d_in[16];
  const float* bo = (const float*)d_in[17];
  const float* pscale = (const float*)d_in[18];
  float* out = (float*)d_out;
  float* ws = (float*)d_ws;

  const size_t NTOK = (size_t)BB * LL;  // 2048
  float* x = ws;
  float* qsb = x + NTOK * CCH;
  float* ksb = qsb + NTOK * CCH;
  float* vsb = ksb + NTOK * CCH;
  float* qpb = vsb + NTOK * CCH;
  float* kpb = qpb + NTOK * 96;
  float* outsb = kpb + NTOK * 96;  // ~22.5 MB total

  ln_kernel<<<dim3((unsigned)NTOK), 256, 0, stream>>>(features, ln_g, ln_b, x);

  proj_fused<<<dim3(28, (unsigned)(NTOK / 64)), 256, 0, stream>>>(
      x, wq, bq, wk, bk, wv, bv, wqp, bqp, wkp, bkp, qsb, ksb, vsb, qpb, kpb);

  ipa_attn2<<<dim3(32, BB * HH), 256, 0, stream>>>(qsb, ksb, vsb, qpb, kpb, pscale, outsb);

  out_proj<<<dim3(8, (unsigned)(NTOK / 64)), 256, 0, stream>>>(outsb, wo, bo, out);
}

// Round 3
// 252.788 us; speedup vs baseline: 3.1054x; 3.1054x over previous
//
#include <hip/hip_runtime.h>
#include <math.h>

#define BB 2
#define LL 1024
#define CCH 512
#define HH 8
#define LN_EPSF 1e-5f

typedef short s16x8 __attribute__((ext_vector_type(8)));
typedef float fx4 __attribute__((ext_vector_type(4)));

__device__ __forceinline__ unsigned short f2bf(float f) {
  unsigned u = __float_as_uint(f);
  unsigned r = (u + 0x7FFFu + ((u >> 16) & 1u)) >> 16;
  return (unsigned short)r;
}
__device__ __forceinline__ float bf2f(unsigned short h) {
  return __uint_as_float(((unsigned)h) << 16);
}
__device__ __forceinline__ s16x8 ldfrag(const unsigned short* p) {
  int4 t = *(const int4*)p;
  return *(s16x8*)&t;
}
__device__ __forceinline__ float wave_sum(float v) {
#pragma unroll
  for (int off = 32; off > 0; off >>= 1) v += __shfl_xor(v, off);
  return v;
}

// ---------------- LayerNorm -> split bf16 hi/lo ----------------
__global__ __launch_bounds__(256) void ln_split(const float* __restrict__ f,
                                                const float* __restrict__ g,
                                                const float* __restrict__ bta,
                                                unsigned short* __restrict__ xh,
                                                unsigned short* __restrict__ xl) {
  const int row = blockIdx.x;
  const int tid = threadIdx.x;
  const int wave = tid >> 6, lane = tid & 63;
  __shared__ float red[8];
  const float* fr = f + (size_t)row * CCH;
  float2 v = *(const float2*)&fr[tid * 2];
  float s = wave_sum(v.x + v.y);
  if (lane == 0) red[wave] = s;
  __syncthreads();
  float mu = (red[0] + red[1] + red[2] + red[3]) * (1.0f / CCH);
  float dx = v.x - mu, dy = v.y - mu;
  float sq = wave_sum(dx * dx + dy * dy);
  if (lane == 0) red[4 + wave] = sq;
  __syncthreads();
  float var = (red[4] + red[5] + red[6] + red[7]) * (1.0f / CCH);
  float inv = 1.0f / sqrtf(var + LN_EPSF);
  float2 gg = *(const float2*)&g[tid * 2];
  float2 bb = *(const float2*)&bta[tid * 2];
  float ox = dx * inv * gg.x + bb.x;
  float oy = dy * inv * gg.y + bb.y;
  unsigned short h0 = f2bf(ox), h1 = f2bf(oy);
  ushort2 hv; hv.x = h0; hv.y = h1;
  ushort2 lv; lv.x = f2bf(ox - bf2f(h0)); lv.y = f2bf(oy - bf2f(h1));
  *(ushort2*)&xh[(size_t)row * CCH + tid * 2] = hv;
  *(ushort2*)&xl[(size_t)row * CCH + tid * 2] = lv;
}

// ---------------- Weight pack: W[k][n] fp32 -> Wt_hi/lo[n][k] bf16 ----------------
// wt row map: q:0, k:512, v:1024, o:1536, qp:2048(+96), kp:2144(+96)
__global__ __launch_bounds__(256) void pack_w(
    const float* __restrict__ wq, const float* __restrict__ wk,
    const float* __restrict__ wv, const float* __restrict__ wo,
    const float* __restrict__ wqp, const float* __restrict__ wkp,
    unsigned short* __restrict__ wt_h, unsigned short* __restrict__ wt_l) {
  __shared__ unsigned short lh[64][65];
  __shared__ unsigned short ll_[64][65];
  const int bx = blockIdx.x;
  const float* W;
  int Ncols, rowbase, kt, nt;
  if (bx < 256) {
    int mat = bx >> 6, t = bx & 63;
    kt = t >> 3; nt = t & 7; Ncols = 512;
    if (mat == 0) { W = wq; rowbase = 0; }
    else if (mat == 1) { W = wk; rowbase = 512; }
    else if (mat == 2) { W = wv; rowbase = 1024; }
    else { W = wo; rowbase = 1536; }
  } else {
    int r = bx - 256; int mat = r >> 4; int t = r & 15;
    kt = t >> 1; nt = t & 1; Ncols = 96;
    if (mat == 0) { W = wqp; rowbase = 2048; }
    else { W = wkp; rowbase = 2144; }
  }
  const int tid = threadIdx.x;
  const int k0 = kt * 64, n0 = nt * 64;
  const int c = tid & 63;
#pragma unroll
  for (int ii = 0; ii < 16; ++ii) {
    int r = ii * 4 + (tid >> 6);
    float val = (n0 + c < Ncols) ? W[(size_t)(k0 + r) * Ncols + n0 + c] : 0.f;
    unsigned short h = f2bf(val);
    lh[r][c] = h;
    ll_[r][c] = f2bf(val - bf2f(h));
  }
  __syncthreads();
  const int n = tid >> 2, kq = tid & 3;
  if (n0 + n < Ncols) {
    unsigned short th[16] __attribute__((aligned(16)));
    unsigned short tl[16] __attribute__((aligned(16)));
#pragma unroll
    for (int kk = 0; kk < 16; ++kk) {
      th[kk] = lh[kq * 16 + kk][n];
      tl[kk] = ll_[kq * 16 + kk][n];
    }
    unsigned short* dh = &wt_h[(size_t)(rowbase + n0 + n) * 512 + k0 + kq * 16];
    unsigned short* dl = &wt_l[(size_t)(rowbase + n0 + n) * 512 + k0 + kq * 16];
    *(int4*)dh = *(int4*)&th[0];
    *(int4*)(dh + 8) = *(int4*)&th[8];
    *(int4*)dl = *(int4*)&tl[0];
    *(int4*)(dl + 8) = *(int4*)&tl[8];
  }
}

// ---------------- Split-bf16 MFMA GEMM core (no LDS; VMEM-direct frags) ----------------
// out[M,N] = A(hi+lo)[M,512] @ Bt(hi+lo)[N,512]^T + bias. Block 256 = 4 waves,
// block tile 128x128, wave tile 64x64 (4x4 frags of 16x16x32).
__device__ __forceinline__ void gemm_core(
    const unsigned short* __restrict__ Ah, const unsigned short* __restrict__ Al,
    const unsigned short* __restrict__ Bth, const unsigned short* __restrict__ Btl,
    const float* __restrict__ bias, float* __restrict__ out,
    int N, int m0blk, int nb) {
  const int tid = threadIdx.x;
  const int wave = __builtin_amdgcn_readfirstlane(tid >> 6);
  const int lane = tid & 63;
  const int quad = lane >> 4, l16 = lane & 15;
  const int m0 = m0blk + (wave & 1) * 64;
  const int n0 = nb + (wave >> 1) * 64;
  fx4 acc[4][4];
#pragma unroll
  for (int i = 0; i < 4; ++i)
#pragma unroll
    for (int j = 0; j < 4; ++j) acc[i][j] = (fx4){0.f, 0.f, 0.f, 0.f};

  for (int ks = 0; ks < 16; ++ks) {
    const int k = ks * 32 + quad * 8;
    s16x8 ah[4], al[4], bh[4], bl[4];
#pragma unroll
    for (int i = 0; i < 4; ++i) {
      size_t off = (size_t)(m0 + i * 16 + l16) * 512 + k;
      ah[i] = ldfrag(&Ah[off]);
      al[i] = ldfrag(&Al[off]);
    }
#pragma unroll
    for (int j = 0; j < 4; ++j) {
      int n = n0 + j * 16 + l16;
      if (n > N - 1) n = N - 1;
      size_t off = (size_t)n * 512 + k;
      bh[j] = ldfrag(&Bth[off]);
      bl[j] = ldfrag(&Btl[off]);
    }
#pragma unroll
    for (int i = 0; i < 4; ++i)
#pragma unroll
      for (int j = 0; j < 4; ++j) {
        acc[i][j] = __builtin_amdgcn_mfma_f32_16x16x32_bf16(ah[i], bh[j], acc[i][j], 0, 0, 0);
        acc[i][j] = __builtin_amdgcn_mfma_f32_16x16x32_bf16(ah[i], bl[j], acc[i][j], 0, 0, 0);
        acc[i][j] = __builtin_amdgcn_mfma_f32_16x16x32_bf16(al[i], bh[j], acc[i][j], 0, 0, 0);
      }
  }
#pragma unroll
  for (int j = 0; j < 4; ++j) {
    int n = n0 + j * 16 + l16;
    if (n < N) {
      float bv = bias[n];
#pragma unroll
      for (int i = 0; i < 4; ++i)
#pragma unroll
        for (int reg = 0; reg < 4; ++reg) {
          int row = m0 + i * 16 + quad * 4 + reg;
          out[(size_t)row * N + n] = acc[i][j][reg] + bv;
        }
    }
  }
}

// Fused q/k/v/qp/kp projections. grid (14, 16).
__global__ __launch_bounds__(256) void proj_mfma(
    const unsigned short* __restrict__ xh, const unsigned short* __restrict__ xl,
    const unsigned short* __restrict__ wt_h, const unsigned short* __restrict__ wt_l,
    const float* __restrict__ bq, const float* __restrict__ bk,
    const float* __restrict__ bv, const float* __restrict__ bqp,
    const float* __restrict__ bkp, float* __restrict__ qsb,
    float* __restrict__ ksb, float* __restrict__ vsb,
    float* __restrict__ qpb, float* __restrict__ kpb) {
  const int bx = blockIdx.x;
  const float* bias; float* out; int N, nb; size_t rb;
  if (bx < 4) { rb = 0; bias = bq; out = qsb; N = 512; nb = bx * 128; }
  else if (bx < 8) { rb = 512; bias = bk; out = ksb; N = 512; nb = (bx - 4) * 128; }
  else if (bx < 12) { rb = 1024; bias = bv; out = vsb; N = 512; nb = (bx - 8) * 128; }
  else if (bx == 12) { rb = 2048; bias = bqp; out = qpb; N = 96; nb = 0; }
  else { rb = 2144; bias = bkp; out = kpb; N = 96; nb = 0; }
  gemm_core(xh, xl, wt_h + rb * 512, wt_l + rb * 512, bias, out, N,
            blockIdx.y * 128, nb);
}

// Output projection. grid (4, 16).
__global__ __launch_bounds__(256) void out_proj_mfma(
    const unsigned short* __restrict__ oh, const unsigned short* __restrict__ ol,
    const unsigned short* __restrict__ wt_h, const unsigned short* __restrict__ wt_l,
    const float* __restrict__ bo, float* __restrict__ out) {
  gemm_core(oh, ol, wt_h + (size_t)1536 * 512, wt_l + (size_t)1536 * 512, bo, out,
            512, blockIdx.y * 128, blockIdx.x * 128);
}

// ---------------- Pack Q~/K~ (bf16, scales folded, K=96 padded) + sq sums ----------------
// grid (256, 16): wave w handles row l = bx*4+w of (b,h)=by.
__global__ __launch_bounds__(256) void pack_qk(
    const float* __restrict__ qsb, const float* __restrict__ qpb,
    const float* __restrict__ ksb, const float* __restrict__ kpb,
    const float* __restrict__ pscale, unsigned short* __restrict__ qt,
    unsigned short* __restrict__ kt_, float* __restrict__ qsqs,
    float* __restrict__ ksqs) {
  const int bh = blockIdx.y;
  const int b = bh >> 3, h = bh & 7;
  const int wave = threadIdx.x >> 6, lane = threadIdx.x & 63;
  const int l = blockIdx.x * 4 + wave;
  const float ps = pscale[h];
  const float s_pt = sqrtf(2.f * ps);
  const size_t rowS = (size_t)(b * LL + l) * CCH + h * 64;
  const size_t rowP = (size_t)(b * LL + l) * 96 + h * 12;
  const size_t orow = (size_t)(bh * LL + l) * 96;
  {
    float v = qsb[rowS + lane] * 0.35355339059f;
    qt[orow + lane] = f2bf(v);
    float vp = (lane < 12) ? qpb[rowP + lane] : 0.f;
    float sq = wave_sum(vp * vp);
    if (lane < 32) qt[orow + 64 + lane] = (lane < 12) ? f2bf(vp * s_pt) : 0;
    if (lane == 0) qsqs[bh * LL + l] = ps * sq;
  }
  {
    float v = ksb[rowS + lane] * 0.35355339059f;
    kt_[orow + lane] = f2bf(v);
    float vp = (lane < 12) ? kpb[rowP + lane] : 0.f;
    float sq = wave_sum(vp * vp);
    if (lane < 32) kt_[orow + 64 + lane] = (lane < 12) ? f2bf(vp * s_pt) : 0;
    if (lane == 0) ksqs[bh * LL + l] = ps * sq;
  }
}

// ---------------- Pack V: vsb fp32 -> Vt_hi/lo[bh][d][l] bf16 (transposed) ----------------
__global__ __launch_bounds__(256) void pack_v(const float* __restrict__ vsb,
                                              unsigned short* __restrict__ vth,
                                              unsigned short* __restrict__ vtl) {
  __shared__ float ld[64][65];
  const int bz = blockIdx.x;  // bh*16 + ltile
  const int bh = bz >> 4, lt = bz & 15;
  const int b = bh >> 3, h = bh & 7;
  const int l0 = lt * 64;
  const int tid = threadIdx.x;
  const int c = tid & 63;
#pragma unroll
  for (int ii = 0; ii < 16; ++ii) {
    int r = ii * 4 + (tid >> 6);
    ld[r][c] = vsb[(size_t)(b * LL + l0 + r) * CCH + h * 64 + c];
  }
  __syncthreads();
  const int d = tid >> 2, lq = tid & 3;
  unsigned short th[16] __attribute__((aligned(16)));
  unsigned short tl[16] __attribute__((aligned(16)));
#pragma unroll
  for (int kk = 0; kk < 16; ++kk) {
    float v = ld[lq * 16 + kk][d];
    unsigned short hh = f2bf(v);
    th[kk] = hh;
    tl[kk] = f2bf(v - bf2f(hh));
  }
  unsigned short* dh = &vth[((size_t)(bh * 64 + d)) * LL + l0 + lq * 16];
  unsigned short* dl = &vtl[((size_t)(bh * 64 + d)) * LL + l0 + lq * 16];
  *(int4*)dh = *(int4*)&th[0];
  *(int4*)(dh + 8) = *(int4*)&th[8];
  *(int4*)dl = *(int4*)&tl[0];
  *(int4*)(dl + 8) = *(int4*)&tl[8];
}

// ---------------- Flash IPA attention via MFMA ----------------
// grid (32 q-tiles of 32 rows, 16 bh); block 256 = 4 waves:
// wave = (khalf<<1)|mstrip: M-strip 16 rows x key-half 32 keys per 64-key tile.
// Q~ frags in registers; K~/V frags VMEM-direct; P transposed via 2KB LDS/wave;
// flash-decoding merge across key-halves at the end.
__global__ __launch_bounds__(256) void ipa_attn_mfma(
    const unsigned short* __restrict__ qt, const unsigned short* __restrict__ kt_,
    const float* __restrict__ qsqs, const float* __restrict__ ksqs,
    const unsigned short* __restrict__ vth, const unsigned short* __restrict__ vtl,
    unsigned short* __restrict__ oh, unsigned short* __restrict__ ol) {
  const int qtile = blockIdx.x;
  const int bh = blockIdx.y;
  const int b = bh >> 3, h = bh & 7;
  const int tid = threadIdx.x;
  const int wave = tid >> 6, lane = tid & 63;
  const int quad = lane >> 4, l16 = lane & 15;
  const int mstrip = wave & 1, khalf = wave >> 1;
  const int ibase = qtile * 32 + mstrip * 16;

  __shared__ unsigned short pb[4][16][32];
  __shared__ float obuf[4][16][64];
  __shared__ float mred[4][16], lred[4][16];

  s16x8 aq[3];
#pragma unroll
  for (int s = 0; s < 3; ++s)
    aq[s] = ldfrag(&qt[(size_t)(bh * LL + ibase + l16) * 96 + s * 32 + quad * 8]);
  float qs_r[4];
#pragma unroll
  for (int reg = 0; reg < 4; ++reg)
    qs_r[reg] = qsqs[bh * LL + ibase + quad * 4 + reg];

  fx4 o[4];
#pragma unroll
  for (int f = 0; f < 4; ++f) o[f] = (fx4){0.f, 0.f, 0.f, 0.f};
  float m_r[4], l_r[4];
#pragma unroll
  for (int reg = 0; reg < 4; ++reg) { m_r[reg] = -INFINITY; l_r[reg] = 0.f; }

  for (int kt2 = 0; kt2 < 16; ++kt2) {
    const int j0 = kt2 * 64 + khalf * 32;
    fx4 sa[2];
    sa[0] = (fx4){0.f, 0.f, 0.f, 0.f};
    sa[1] = (fx4){0.f, 0.f, 0.f, 0.f};
#pragma unroll
    for (int f = 0; f < 2; ++f)
#pragma unroll
      for (int s = 0; s < 3; ++s) {
        s16x8 bk = ldfrag(&kt_[(size_t)(bh * LL + j0 + f * 16 + l16) * 96 + s * 32 + quad * 8]);
        sa[f] = __builtin_amdgcn_mfma_f32_16x16x32_bf16(aq[s], bk, sa[f], 0, 0, 0);
      }
    float ks0 = ksqs[bh * LL + j0 + l16];
    float ks1 = ksqs[bh * LL + j0 + 16 + l16];
#pragma unroll
    for (int reg = 0; reg < 4; ++reg) {
      float z0 = sa[0][reg] - qs_r[reg] - ks0;
      float z1 = sa[1][reg] - qs_r[reg] - ks1;
      float mx = fmaxf(z0, z1);
#pragma unroll
      for (int off = 8; off > 0; off >>= 1) mx = fmaxf(mx, __shfl_xor(mx, off));
      float mnew = fmaxf(m_r[reg], mx);
      float p0 = __expf(z0 - mnew), p1 = __expf(z1 - mnew);
      float alpha = __expf(m_r[reg] - mnew);
      float psum = p0 + p1;
#pragma unroll
      for (int off = 8; off > 0; off >>= 1) psum += __shfl_xor(psum, off);
      l_r[reg] = l_r[reg] * alpha + psum;
      m_r[reg] = mnew;
      o[0][reg] *= alpha; o[1][reg] *= alpha; o[2][reg] *= alpha; o[3][reg] *= alpha;
      pb[wave][quad * 4 + reg][l16] = f2bf(p0);
      pb[wave][quad * 4 + reg][16 + l16] = f2bf(p1);
    }
    s16x8 ap = ldfrag(&pb[wave][l16][quad * 8]);
#pragma unroll
    for (int f = 0; f < 4; ++f) {
      size_t voff = ((size_t)(bh * 64 + f * 16 + l16)) * LL + j0 + quad * 8;
      s16x8 bvh = ldfrag(&vth[voff]);
      s16x8 bvl = ldfrag(&vtl[voff]);
      o[f] = __builtin_amdgcn_mfma_f32_16x16x32_bf16(ap, bvh, o[f], 0, 0, 0);
      o[f] = __builtin_amdgcn_mfma_f32_16x16x32_bf16(ap, bvl, o[f], 0, 0, 0);
    }
  }
  if (l16 == 0) {
#pragma unroll
    for (int reg = 0; reg < 4; ++reg) {
      mred[wave][quad * 4 + reg] = m_r[reg];
      lred[wave][quad * 4 + reg] = l_r[reg];
    }
  }
#pragma unroll
  for (int f = 0; f < 4; ++f)
#pragma unroll
    for (int reg = 0; reg < 4; ++reg)
      obuf[wave][quad * 4 + reg][f * 16 + l16] = o[f][reg];
  __syncthreads();
  if (khalf == 0) {
    const int pw = wave + 2;
#pragma unroll
    for (int f = 0; f < 4; ++f)
#pragma unroll
      for (int reg = 0; reg < 4; ++reg) {
        int row = quad * 4 + reg;
        int d = f * 16 + l16;
        float m0v = mred[wave][row], m1v = mred[pw][row];
        float l0v = lred[wave][row], l1v = lred[pw][row];
        float M = fmaxf(m0v, m1v);
        float w0 = __expf(m0v - M), w1 = __expf(m1v - M);
        float Lv = l0v * w0 + l1v * w1;
        float val = (obuf[wave][row][d] * w0 + obuf[pw][row][d] * w1) / Lv;
        unsigned short hv = f2bf(val);
        size_t addr = (size_t)(b * LL + ibase + row) * CCH + h * 64 + d;
        oh[addr] = hv;
        ol[addr] = f2bf(val - bf2f(hv));
      }
  }
}

extern "C" void kernel_launch(void* const* d_in, const int* in_sizes, int n_in,
                              void* d_out, int out_size, void* d_ws, size_t ws_size,
                              hipStream_t stream) {
  (void)in_sizes; (void)n_in; (void)out_size; (void)ws_size;
  const float* features = (const float*)d_in[0];
  const float* ln_g = (const float*)d_in[2];
  const float* ln_b = (const float*)d_in[3];
  const float* wq = (const float*)d_in[4];
  const float* bq = (const float*)d_in[5];
  const float* wk = (const float*)d_in[6];
  const float* bk = (const float*)d_in[7];
  const float* wv = (const float*)d_in[8];
  const float* bv = (const float*)d_in[9];
  const float* wqp = (const float*)d_in[10];
  const float* bqp = (const float*)d_in[11];
  const float* wkp = (const float*)d_in[12];
  const float* bkp = (const float*)d_in[13];
  const float* wo = (const float*)d_in[16];
  const float* bo = (const float*)d_in[17];
  const float* pscale = (const float*)d_in[18];
  float* out = (float*)d_out;

  char* cur = (char*)d_ws;
  const size_t NTOK = (size_t)BB * LL;  // 2048
  unsigned short* xh = (unsigned short*)cur; cur += NTOK * CCH * 2;
  unsigned short* xl = (unsigned short*)cur; cur += NTOK * CCH * 2;
  unsigned short* wt_h = (unsigned short*)cur; cur += (size_t)2240 * 512 * 2;
  unsigned short* wt_l = (unsigned short*)cur; cur += (size_t)2240 * 512 * 2;
  float* qsb = (float*)cur; cur += NTOK * CCH * 4;
  float* ksb = (float*)cur; cur += NTOK * CCH * 4;
  float* vsb = (float*)cur; cur += NTOK * CCH * 4;
  float* qpb = (float*)cur; cur += NTOK * 96 * 4;
  float* kpb = (float*)cur; cur += NTOK * 96 * 4;
  unsigned short* qt = (unsigned short*)cur; cur += (size_t)16 * LL * 96 * 2;
  unsigned short* kt_ = (unsigned short*)cur; cur += (size_t)16 * LL * 96 * 2;
  float* qsqs = (float*)cur; cur += (size_t)16 * LL * 4;
  float* ksqs = (float*)cur; cur += (size_t)16 * LL * 4;
  unsigned short* vth = (unsigned short*)cur; cur += (size_t)16 * 64 * LL * 2;
  unsigned short* vtl = (unsigned short*)cur; cur += (size_t)16 * 64 * LL * 2;
  unsigned short* oh = (unsigned short*)cur; cur += NTOK * CCH * 2;
  unsigned short* ol = (unsigned short*)cur; cur += NTOK * CCH * 2;

  ln_split<<<dim3((unsigned)NTOK), 256, 0, stream>>>(features, ln_g, ln_b, xh, xl);
  pack_w<<<dim3(288), 256, 0, stream>>>(wq, wk, wv, wo, wqp, wkp, wt_h, wt_l);
  proj_mfma<<<dim3(14, 16), 256, 0, stream>>>(xh, xl, wt_h, wt_l, bq, bk, bv, bqp,
                                              bkp, qsb, ksb, vsb, qpb, kpb);
  pack_qk<<<dim3(256, 16), 256, 0, stream>>>(qsb, qpb, ksb, kpb, pscale, qt, kt_,
                                             qsqs, ksqs);
  pack_v<<<dim3(256), 256, 0, stream>>>(vsb, vth, vtl);
  ipa_attn_mfma<<<dim3(32, 16), 256, 0, stream>>>(qt, kt_, qsqs, ksqs, vth, vtl,
                                                  oh, ol);
  out_proj_mfma<<<dim3(4, 16), 256, 0, stream>>>(oh, ol, wt_h, wt_l, bo, out);
}

// Round 4
// 240.985 us; speedup vs baseline: 3.2575x; 1.0490x over previous
//
#include <hip/hip_runtime.h>
#include <math.h>

#define BB 2
#define LL 1024
#define CCH 512
#define HH 8
#define LN_EPSF 1e-5f

typedef short s16x8 __attribute__((ext_vector_type(8)));
typedef float fx4 __attribute__((ext_vector_type(4)));

__device__ __forceinline__ unsigned short f2bf(float f) {
  unsigned u = __float_as_uint(f);
  unsigned r = (u + 0x7FFFu + ((u >> 16) & 1u)) >> 16;
  return (unsigned short)r;
}
__device__ __forceinline__ float bf2f(unsigned short h) {
  return __uint_as_float(((unsigned)h) << 16);
}
__device__ __forceinline__ s16x8 ldfrag(const unsigned short* p) {
  int4 t = *(const int4*)p;
  return *(s16x8*)&t;
}

// ---- DPP row_ror reductions over 16-lane rows (VALU pipe, no LDS/shuffle) ----
template <int CTRL>
__device__ __forceinline__ float dpp_mov(float x) {
  return __int_as_float(
      __builtin_amdgcn_update_dpp(0, __float_as_int(x), CTRL, 0xF, 0xF, true));
}
__device__ __forceinline__ float red16_sum(float v) {
  v += dpp_mov<0x121>(v);  // row_ror:1
  v += dpp_mov<0x122>(v);  // row_ror:2
  v += dpp_mov<0x124>(v);  // row_ror:4
  v += dpp_mov<0x128>(v);  // row_ror:8
  return v;
}
__device__ __forceinline__ float red16_max(float v) {
  v = fmaxf(v, dpp_mov<0x121>(v));
  v = fmaxf(v, dpp_mov<0x122>(v));
  v = fmaxf(v, dpp_mov<0x124>(v));
  v = fmaxf(v, dpp_mov<0x128>(v));
  return v;
}
__device__ __forceinline__ float wave_sum(float v) {
  v = red16_sum(v);            // row sums (4 VALU-DPP)
  v += __shfl_xor(v, 16);      // 2 remaining cross-row stages
  v += __shfl_xor(v, 32);
  return v;
}

// ---------------- LayerNorm -> split bf16 hi/lo ----------------
__global__ __launch_bounds__(256) void ln_split(const float* __restrict__ f,
                                                const float* __restrict__ g,
                                                const float* __restrict__ bta,
                                                unsigned short* __restrict__ xh,
                                                unsigned short* __restrict__ xl) {
  const int row = blockIdx.x;
  const int tid = threadIdx.x;
  const int wave = tid >> 6, lane = tid & 63;
  __shared__ float red[8];
  const float* fr = f + (size_t)row * CCH;
  float2 v = *(const float2*)&fr[tid * 2];
  float s = wave_sum(v.x + v.y);
  if (lane == 0) red[wave] = s;
  __syncthreads();
  float mu = (red[0] + red[1] + red[2] + red[3]) * (1.0f / CCH);
  float dx = v.x - mu, dy = v.y - mu;
  float sq = wave_sum(dx * dx + dy * dy);
  if (lane == 0) red[4 + wave] = sq;
  __syncthreads();
  float var = (red[4] + red[5] + red[6] + red[7]) * (1.0f / CCH);
  float inv = 1.0f / sqrtf(var + LN_EPSF);
  float2 gg = *(const float2*)&g[tid * 2];
  float2 bb = *(const float2*)&bta[tid * 2];
  float ox = dx * inv * gg.x + bb.x;
  float oy = dy * inv * gg.y + bb.y;
  unsigned short h0 = f2bf(ox), h1 = f2bf(oy);
  ushort2 hv; hv.x = h0; hv.y = h1;
  ushort2 lv; lv.x = f2bf(ox - bf2f(h0)); lv.y = f2bf(oy - bf2f(h1));
  *(ushort2*)&xh[(size_t)row * CCH + tid * 2] = hv;
  *(ushort2*)&xl[(size_t)row * CCH + tid * 2] = lv;
}

// ---------------- Weight pack: W[k][n] fp32 -> Wt_hi/lo[n][k] bf16 ----------------
// wt row map: q:0, k:512, v:1024, o:1536, qp:2048(+96), kp:2144(+96)
__global__ __launch_bounds__(256) void pack_w(
    const float* __restrict__ wq, const float* __restrict__ wk,
    const float* __restrict__ wv, const float* __restrict__ wo,
    const float* __restrict__ wqp, const float* __restrict__ wkp,
    unsigned short* __restrict__ wt_h, unsigned short* __restrict__ wt_l) {
  __shared__ unsigned short lh[64][65];
  __shared__ unsigned short ll_[64][65];
  const int bx = blockIdx.x;
  const float* W;
  int Ncols, rowbase, kt, nt;
  if (bx < 256) {
    int mat = bx >> 6, t = bx & 63;
    kt = t >> 3; nt = t & 7; Ncols = 512;
    if (mat == 0) { W = wq; rowbase = 0; }
    else if (mat == 1) { W = wk; rowbase = 512; }
    else if (mat == 2) { W = wv; rowbase = 1024; }
    else { W = wo; rowbase = 1536; }
  } else {
    int r = bx - 256; int mat = r >> 4; int t = r & 15;
    kt = t >> 1; nt = t & 1; Ncols = 96;
    if (mat == 0) { W = wqp; rowbase = 2048; }
    else { W = wkp; rowbase = 2144; }
  }
  const int tid = threadIdx.x;
  const int k0 = kt * 64, n0 = nt * 64;
  const int c = tid & 63;
#pragma unroll
  for (int ii = 0; ii < 16; ++ii) {
    int r = ii * 4 + (tid >> 6);
    float val = (n0 + c < Ncols) ? W[(size_t)(k0 + r) * Ncols + n0 + c] : 0.f;
    unsigned short h = f2bf(val);
    lh[r][c] = h;
    ll_[r][c] = f2bf(val - bf2f(h));
  }
  __syncthreads();
  const int n = tid >> 2, kq = tid & 3;
  if (n0 + n < Ncols) {
    unsigned short th[16] __attribute__((aligned(16)));
    unsigned short tl[16] __attribute__((aligned(16)));
#pragma unroll
    for (int kk = 0; kk < 16; ++kk) {
      th[kk] = lh[kq * 16 + kk][n];
      tl[kk] = ll_[kq * 16 + kk][n];
    }
    unsigned short* dh = &wt_h[(size_t)(rowbase + n0 + n) * 512 + k0 + kq * 16];
    unsigned short* dl = &wt_l[(size_t)(rowbase + n0 + n) * 512 + k0 + kq * 16];
    *(int4*)dh = *(int4*)&th[0];
    *(int4*)(dh + 8) = *(int4*)&th[8];
    *(int4*)dl = *(int4*)&tl[0];
    *(int4*)(dl + 8) = *(int4*)&tl[8];
  }
}

// ---------------- Split-bf16 MFMA accumulate core ----------------
// Block tile 64 (M) x NF*32 (N); 4 waves = 2 m-halves x 2 n-halves.
// Wave tile 32 x NF*16. VMEM-direct fragments, K=512.
template <int NF>
__device__ __forceinline__ void mfma_acc(
    const unsigned short* __restrict__ Ah, const unsigned short* __restrict__ Al,
    const unsigned short* __restrict__ Bth, const unsigned short* __restrict__ Btl,
    int m0, int n0, int Nrows, fx4 acc[2][NF]) {
  const int tid = threadIdx.x;
  const int wave = __builtin_amdgcn_readfirstlane(tid >> 6);
  const int lane = tid & 63;
  const int quad = lane >> 4, l16 = lane & 15;
  const int mw = m0 + (wave & 1) * 32;
  const int nw = n0 + (wave >> 1) * (NF * 16);
#pragma unroll
  for (int i = 0; i < 2; ++i)
#pragma unroll
    for (int j = 0; j < NF; ++j) acc[i][j] = (fx4){0.f, 0.f, 0.f, 0.f};

  for (int ks = 0; ks < 16; ++ks) {
    const int k = ks * 32 + quad * 8;
    s16x8 ah[2], al[2], bh[NF], bl[NF];
#pragma unroll
    for (int i = 0; i < 2; ++i) {
      size_t off = (size_t)(mw + i * 16 + l16) * 512 + k;
      ah[i] = ldfrag(&Ah[off]);
      al[i] = ldfrag(&Al[off]);
    }
#pragma unroll
    for (int j = 0; j < NF; ++j) {
      int n = nw + j * 16 + l16;
      if (n > Nrows - 1) n = Nrows - 1;
      size_t off = (size_t)n * 512 + k;
      bh[j] = ldfrag(&Bth[off]);
      bl[j] = ldfrag(&Btl[off]);
    }
#pragma unroll
    for (int i = 0; i < 2; ++i)
#pragma unroll
      for (int j = 0; j < NF; ++j) {
        acc[i][j] = __builtin_amdgcn_mfma_f32_16x16x32_bf16(ah[i], bh[j], acc[i][j], 0, 0, 0);
        acc[i][j] = __builtin_amdgcn_mfma_f32_16x16x32_bf16(ah[i], bl[j], acc[i][j], 0, 0, 0);
        acc[i][j] = __builtin_amdgcn_mfma_f32_16x16x32_bf16(al[i], bh[j], acc[i][j], 0, 0, 0);
      }
  }
}

// Fused projections writing PACKED outputs. grid (14, 32).
// bx 0..3: q scalar -> qt cols 0..63 (scaled 1/sqrt(8))
// bx 4..7: k scalar -> kt
// bx 8..11: v -> vsb fp32
// bx 12: qp point -> qt cols 64..75 (scaled sqrt(2*ps_h)); 13: kp -> kt
__global__ __launch_bounds__(256) void proj_mfma(
    const unsigned short* __restrict__ xh, const unsigned short* __restrict__ xl,
    const unsigned short* __restrict__ wt_h, const unsigned short* __restrict__ wt_l,
    const float* __restrict__ bq, const float* __restrict__ bk,
    const float* __restrict__ bv, const float* __restrict__ bqp,
    const float* __restrict__ bkp, const float* __restrict__ pscale,
    unsigned short* __restrict__ qt, unsigned short* __restrict__ kt_,
    float* __restrict__ vsb) {
  const int bx = blockIdx.x;
  const int m0 = blockIdx.y * 64;
  const float* bias;
  size_t rb; int nb, Nrows, mode;  // mode 0=scalar pack,1=v fp32,2=point pack
  unsigned short* pdst = qt;
  if (bx < 4) { rb = 0; bias = bq; nb = bx * 128; Nrows = 512; mode = 0; pdst = qt; }
  else if (bx < 8) { rb = 512; bias = bk; nb = (bx - 4) * 128; Nrows = 512; mode = 0; pdst = kt_; }
  else if (bx < 12) { rb = 1024; bias = bv; nb = (bx - 8) * 128; Nrows = 512; mode = 1; }
  else if (bx == 12) { rb = 2048; bias = bqp; nb = 0; Nrows = 96; mode = 2; pdst = qt; }
  else { rb = 2144; bias = bkp; nb = 0; Nrows = 96; mode = 2; pdst = kt_; }

  fx4 acc[2][4];
  mfma_acc<4>(xh, xl, wt_h + rb * 512, wt_l + rb * 512, m0, nb, Nrows, acc);

  const int tid = threadIdx.x;
  const int wave = __builtin_amdgcn_readfirstlane(tid >> 6);
  const int lane = tid & 63;
  const int quad = lane >> 4, l16 = lane & 15;
  const int mw = m0 + (wave & 1) * 32;
  const int nw = nb + (wave >> 1) * 64;

  if (mode == 1) {
#pragma unroll
    for (int j = 0; j < 4; ++j) {
      int n = nw + j * 16 + l16;
      float bb = bias[n];
#pragma unroll
      for (int i = 0; i < 2; ++i)
#pragma unroll
        for (int reg = 0; reg < 4; ++reg) {
          int row = mw + i * 16 + quad * 4 + reg;
          vsb[(size_t)row * 512 + n] = acc[i][j][reg] + bb;
        }
    }
  } else if (mode == 0) {
#pragma unroll
    for (int j = 0; j < 4; ++j) {
      int n = nw + j * 16 + l16;
      int h = n >> 6, d = n & 63;
      float bb = bias[n];
#pragma unroll
      for (int i = 0; i < 2; ++i)
#pragma unroll
        for (int reg = 0; reg < 4; ++reg) {
          int row = mw + i * 16 + quad * 4 + reg;
          int bi = row >> 10, l = row & 1023;
          float val = (acc[i][j][reg] + bb) * 0.35355339059f;  // 1/sqrt(8)
          pdst[((size_t)((bi * 8 + h) * 1024 + l)) * 96 + d] = f2bf(val);
        }
    }
  } else {
#pragma unroll
    for (int j = 0; j < 4; ++j) {
      int n = nw + j * 16 + l16;
      bool ok = n < 96;
      int nn = ok ? n : 0;
      int h = nn / 12, c = nn - h * 12;
      float sc = sqrtf(2.f * pscale[h]);
      float bb = bias[nn];
#pragma unroll
      for (int i = 0; i < 2; ++i)
#pragma unroll
        for (int reg = 0; reg < 4; ++reg) {
          int row = mw + i * 16 + quad * 4 + reg;
          int bi = row >> 10, l = row & 1023;
          float val = (acc[i][j][reg] + bb) * sc;
          if (ok)
            pdst[((size_t)((bi * 8 + h) * 1024 + l)) * 96 + 64 + c] = f2bf(val);
        }
    }
  }
}

// Output projection, 64x64 tiles. grid (8, 32).
__global__ __launch_bounds__(256) void out_proj_mfma(
    const unsigned short* __restrict__ oh, const unsigned short* __restrict__ ol,
    const unsigned short* __restrict__ wt_h, const unsigned short* __restrict__ wt_l,
    const float* __restrict__ bo, float* __restrict__ out) {
  const int m0 = blockIdx.y * 64, n0 = blockIdx.x * 64;
  fx4 acc[2][2];
  mfma_acc<2>(oh, ol, wt_h + (size_t)1536 * 512, wt_l + (size_t)1536 * 512, m0, n0,
              512, acc);
  const int tid = threadIdx.x;
  const int wave = __builtin_amdgcn_readfirstlane(tid >> 6);
  const int lane = tid & 63;
  const int quad = lane >> 4, l16 = lane & 15;
  const int mw = m0 + (wave & 1) * 32;
  const int nw = n0 + (wave >> 1) * 32;
#pragma unroll
  for (int j = 0; j < 2; ++j) {
    int n = nw + j * 16 + l16;
    float bb = bo[n];
#pragma unroll
    for (int i = 0; i < 2; ++i)
#pragma unroll
      for (int reg = 0; reg < 4; ++reg) {
        int row = mw + i * 16 + quad * 4 + reg;
        out[(size_t)row * 512 + n] = acc[i][j][reg] + bb;
      }
  }
}

// ---------------- sq sums from packed Q~/K~ (bf16-consistent) ----------------
// sq = 0.5 * sum(packed_point^2): packed = sqrt(2 ps) * p  =>  0.5*sum = ps*|p|^2.
__global__ __launch_bounds__(256) void pack_sq(const unsigned short* __restrict__ qt,
                                               const unsigned short* __restrict__ kt_,
                                               float* __restrict__ qsqs,
                                               float* __restrict__ ksqs) {
  const int idx = blockIdx.x * 256 + threadIdx.x;  // row in [0, 16*1024)
  {
    const int4* p = (const int4*)&qt[(size_t)idx * 96 + 64];
    float s = 0.f;
#pragma unroll
    for (int u = 0; u < 4; ++u) {
      int4 t = p[u];
      int w[4] = {t.x, t.y, t.z, t.w};
#pragma unroll
      for (int q = 0; q < 4; ++q) {
        float a = __uint_as_float(((unsigned)w[q]) << 16);
        float b2 = __uint_as_float(((unsigned)w[q]) & 0xFFFF0000u);
        s += a * a + b2 * b2;
      }
    }
    qsqs[idx] = 0.5f * s;
  }
  {
    const int4* p = (const int4*)&kt_[(size_t)idx * 96 + 64];
    float s = 0.f;
#pragma unroll
    for (int u = 0; u < 4; ++u) {
      int4 t = p[u];
      int w[4] = {t.x, t.y, t.z, t.w};
#pragma unroll
      for (int q = 0; q < 4; ++q) {
        float a = __uint_as_float(((unsigned)w[q]) << 16);
        float b2 = __uint_as_float(((unsigned)w[q]) & 0xFFFF0000u);
        s += a * a + b2 * b2;
      }
    }
    ksqs[idx] = 0.5f * s;
  }
}

// ---------------- Pack V: vsb fp32 -> Vt_hi/lo[bh][d][l] bf16 (transposed) ----------------
__global__ __launch_bounds__(256) void pack_v(const float* __restrict__ vsb,
                                              unsigned short* __restrict__ vth,
                                              unsigned short* __restrict__ vtl) {
  __shared__ float ld[64][65];
  const int bz = blockIdx.x;  // bh*16 + ltile
  const int bh = bz >> 4, lt = bz & 15;
  const int b = bh >> 3, h = bh & 7;
  const int l0 = lt * 64;
  const int tid = threadIdx.x;
  const int c = tid & 63;
#pragma unroll
  for (int ii = 0; ii < 16; ++ii) {
    int r = ii * 4 + (tid >> 6);
    ld[r][c] = vsb[(size_t)(b * LL + l0 + r) * CCH + h * 64 + c];
  }
  __syncthreads();
  const int d = tid >> 2, lq = tid & 3;
  unsigned short th[16] __attribute__((aligned(16)));
  unsigned short tl[16] __attribute__((aligned(16)));
#pragma unroll
  for (int kk = 0; kk < 16; ++kk) {
    float v = ld[lq * 16 + kk][d];
    unsigned short hh = f2bf(v);
    th[kk] = hh;
    tl[kk] = f2bf(v - bf2f(hh));
  }
  unsigned short* dh = &vth[((size_t)(bh * 64 + d)) * LL + l0 + lq * 16];
  unsigned short* dl = &vtl[((size_t)(bh * 64 + d)) * LL + l0 + lq * 16];
  *(int4*)dh = *(int4*)&th[0];
  *(int4*)(dh + 8) = *(int4*)&th[8];
  *(int4*)dl = *(int4*)&tl[0];
  *(int4*)(dl + 8) = *(int4*)&tl[8];
}

// ---------------- Flash IPA attention via MFMA + DPP softmax ----------------
// grid (32 q-tiles of 32 rows, 16 bh); block 256 = 4 waves:
// wave = (khalf<<1)|mstrip. Softmax reductions are over the 16 l16 lanes of
// each quad (= one DPP row) -> row_ror DPP, zero LDS-pipe ops.
__global__ __launch_bounds__(256) void ipa_attn_mfma(
    const unsigned short* __restrict__ qt, const unsigned short* __restrict__ kt_,
    const float* __restrict__ qsqs, const float* __restrict__ ksqs,
    const unsigned short* __restrict__ vth, const unsigned short* __restrict__ vtl,
    unsigned short* __restrict__ oh, unsigned short* __restrict__ ol) {
  const int qtile = blockIdx.x;
  const int bh = blockIdx.y;
  const int b = bh >> 3, h = bh & 7;
  const int tid = threadIdx.x;
  const int wave = tid >> 6, lane = tid & 63;
  const int quad = lane >> 4, l16 = lane & 15;
  const int mstrip = wave & 1, khalf = wave >> 1;
  const int ibase = qtile * 32 + mstrip * 16;

  __shared__ unsigned short pb[4][16][32];
  __shared__ float obuf[4][16][64];
  __shared__ float mred[4][16], lred[4][16];

  s16x8 aq[3];
#pragma unroll
  for (int s = 0; s < 3; ++s)
    aq[s] = ldfrag(&qt[(size_t)(bh * LL + ibase + l16) * 96 + s * 32 + quad * 8]);
  float qs_r[4];
#pragma unroll
  for (int reg = 0; reg < 4; ++reg)
    qs_r[reg] = qsqs[bh * LL + ibase + quad * 4 + reg];

  fx4 o[4];
#pragma unroll
  for (int f = 0; f < 4; ++f) o[f] = (fx4){0.f, 0.f, 0.f, 0.f};
  float m_r[4], l_r[4];
#pragma unroll
  for (int reg = 0; reg < 4; ++reg) { m_r[reg] = -INFINITY; l_r[reg] = 0.f; }

  for (int kt2 = 0; kt2 < 16; ++kt2) {
    const int j0 = kt2 * 64 + khalf * 32;
    // issue K loads
    s16x8 bk[2][3];
#pragma unroll
    for (int f = 0; f < 2; ++f)
#pragma unroll
      for (int s = 0; s < 3; ++s)
        bk[f][s] = ldfrag(&kt_[(size_t)(bh * LL + j0 + f * 16 + l16) * 96 + s * 32 + quad * 8]);
    // prefetch V (independent of softmax; latency overlaps QK+softmax)
    s16x8 bvh[4], bvl[4];
#pragma unroll
    for (int f = 0; f < 4; ++f) {
      size_t voff = ((size_t)(bh * 64 + f * 16 + l16)) * LL + j0 + quad * 8;
      bvh[f] = ldfrag(&vth[voff]);
      bvl[f] = ldfrag(&vtl[voff]);
    }
    float ks0 = ksqs[bh * LL + j0 + l16];
    float ks1 = ksqs[bh * LL + j0 + 16 + l16];

    fx4 sa[2];
    sa[0] = (fx4){0.f, 0.f, 0.f, 0.f};
    sa[1] = (fx4){0.f, 0.f, 0.f, 0.f};
#pragma unroll
    for (int f = 0; f < 2; ++f)
#pragma unroll
      for (int s = 0; s < 3; ++s)
        sa[f] = __builtin_amdgcn_mfma_f32_16x16x32_bf16(aq[s], bk[f][s], sa[f], 0, 0, 0);

#pragma unroll
    for (int reg = 0; reg < 4; ++reg) {
      float z0 = sa[0][reg] - qs_r[reg] - ks0;
      float z1 = sa[1][reg] - qs_r[reg] - ks1;
      float mx = red16_max(fmaxf(z0, z1));
      float mnew = fmaxf(m_r[reg], mx);
      float p0 = __expf(z0 - mnew), p1 = __expf(z1 - mnew);
      float alpha = __expf(m_r[reg] - mnew);
      float psum = red16_sum(p0 + p1);
      l_r[reg] = l_r[reg] * alpha + psum;
      m_r[reg] = mnew;
      o[0][reg] *= alpha; o[1][reg] *= alpha; o[2][reg] *= alpha; o[3][reg] *= alpha;
      pb[wave][quad * 4 + reg][l16] = f2bf(p0);
      pb[wave][quad * 4 + reg][16 + l16] = f2bf(p1);
    }
    s16x8 ap = ldfrag(&pb[wave][l16][quad * 8]);
#pragma unroll
    for (int f = 0; f < 4; ++f) {
      o[f] = __builtin_amdgcn_mfma_f32_16x16x32_bf16(ap, bvh[f], o[f], 0, 0, 0);
      o[f] = __builtin_amdgcn_mfma_f32_16x16x32_bf16(ap, bvl[f], o[f], 0, 0, 0);
    }
  }
  if (l16 == 0) {
#pragma unroll
    for (int reg = 0; reg < 4; ++reg) {
      mred[wave][quad * 4 + reg] = m_r[reg];
      lred[wave][quad * 4 + reg] = l_r[reg];
    }
  }
#pragma unroll
  for (int f = 0; f < 4; ++f)
#pragma unroll
    for (int reg = 0; reg < 4; ++reg)
      obuf[wave][quad * 4 + reg][f * 16 + l16] = o[f][reg];
  __syncthreads();
  if (khalf == 0) {
    const int pw = wave + 2;
#pragma unroll
    for (int f = 0; f < 4; ++f)
#pragma unroll
      for (int reg = 0; reg < 4; ++reg) {
        int row = quad * 4 + reg;
        int d = f * 16 + l16;
        float m0v = mred[wave][row], m1v = mred[pw][row];
        float l0v = lred[wave][row], l1v = lred[pw][row];
        float M = fmaxf(m0v, m1v);
        float w0 = __expf(m0v - M), w1 = __expf(m1v - M);
        float Lv = l0v * w0 + l1v * w1;
        float val = (obuf[wave][row][d] * w0 + obuf[pw][row][d] * w1) / Lv;
        unsigned short hv = f2bf(val);
        size_t addr = (size_t)(b * LL + ibase + row) * CCH + h * 64 + d;
        oh[addr] = hv;
        ol[addr] = f2bf(val - bf2f(hv));
      }
  }
}

extern "C" void kernel_launch(void* const* d_in, const int* in_sizes, int n_in,
                              void* d_out, int out_size, void* d_ws, size_t ws_size,
                              hipStream_t stream) {
  (void)in_sizes; (void)n_in; (void)out_size; (void)ws_size;
  const float* features = (const float*)d_in[0];
  const float* ln_g = (const float*)d_in[2];
  const float* ln_b = (const float*)d_in[3];
  const float* wq = (const float*)d_in[4];
  const float* bq = (const float*)d_in[5];
  const float* wk = (const float*)d_in[6];
  const float* bk = (const float*)d_in[7];
  const float* wv = (const float*)d_in[8];
  const float* bv = (const float*)d_in[9];
  const float* wqp = (const float*)d_in[10];
  const float* bqp = (const float*)d_in[11];
  const float* wkp = (const float*)d_in[12];
  const float* bkp = (const float*)d_in[13];
  const float* wo = (const float*)d_in[16];
  const float* bo = (const float*)d_in[17];
  const float* pscale = (const float*)d_in[18];
  float* out = (float*)d_out;

  char* cur = (char*)d_ws;
  const size_t NTOK = (size_t)BB * LL;  // 2048
  unsigned short* xh = (unsigned short*)cur; cur += NTOK * CCH * 2;
  unsigned short* xl = (unsigned short*)cur; cur += NTOK * CCH * 2;
  unsigned short* wt_h = (unsigned short*)cur; cur += (size_t)2240 * 512 * 2;
  unsigned short* wt_l = (unsigned short*)cur; cur += (size_t)2240 * 512 * 2;
  float* vsb = (float*)cur; cur += NTOK * CCH * 4;
  unsigned short* qt = (unsigned short*)cur; cur += (size_t)16 * LL * 96 * 2;
  unsigned short* kt_ = (unsigned short*)cur; cur += (size_t)16 * LL * 96 * 2;
  float* qsqs = (float*)cur; cur += (size_t)16 * LL * 4;
  float* ksqs = (float*)cur; cur += (size_t)16 * LL * 4;
  unsigned short* vth = (unsigned short*)cur; cur += (size_t)16 * 64 * LL * 2;
  unsigned short* vtl = (unsigned short*)cur; cur += (size_t)16 * 64 * LL * 2;
  unsigned short* oh = (unsigned short*)cur; cur += NTOK * CCH * 2;
  unsigned short* ol = (unsigned short*)cur; cur += NTOK * CCH * 2;

  // zero the packed Q~/K~ (covers the K=96 pad cols 76..95); qt,kt adjacent
  hipMemsetAsync(qt, 0, (size_t)2 * 16 * LL * 96 * 2, stream);

  ln_split<<<dim3((unsigned)NTOK), 256, 0, stream>>>(features, ln_g, ln_b, xh, xl);
  pack_w<<<dim3(288), 256, 0, stream>>>(wq, wk, wv, wo, wqp, wkp, wt_h, wt_l);
  proj_mfma<<<dim3(14, 32), 256, 0, stream>>>(xh, xl, wt_h, wt_l, bq, bk, bv, bqp,
                                              bkp, pscale, qt, kt_, vsb);
  pack_sq<<<dim3(128), 256, 0, stream>>>(qt, kt_, qsqs, ksqs);
  pack_v<<<dim3(256), 256, 0, stream>>>(vsb, vth, vtl);
  ipa_attn_mfma<<<dim3(32, 16), 256, 0, stream>>>(qt, kt_, qsqs, ksqs, vth, vtl,
                                                  oh, ol);
  out_proj_mfma<<<dim3(8, 32), 256, 0, stream>>>(oh, ol, wt_h, wt_l, bo, out);
}